// Round 11
// baseline (154.413 us; speedup 1.0000x reference)
//
#include <hip/hip_runtime.h>
#include <math.h>

#define DIN   500
#define H1    256   // heads(8) * dim_h(32)
#define H2    128   // heads(8) * dim_out(16)
#define NEG_SLOPE 0.2f

typedef __attribute__((ext_vector_type(8))) short short8;
typedef __attribute__((ext_vector_type(4))) float floatx4;

static __device__ __forceinline__ unsigned short f2bf(float f) {
    union { float f; unsigned int u; } x; x.f = f;
    unsigned int r = x.u + 0x7fffu + ((x.u >> 16) & 1u);   // RNE
    return (unsigned short)(r >> 16);
}
static __device__ __forceinline__ float bitsf(unsigned int i) {
    union { unsigned int i; float f; } x; x.i = i;
    return x.f;
}
// 4 dwords (8 bf16, channel-ordered lo/hi) -> 8 floats
static __device__ __forceinline__ void cvt8(uint4 u, float* o) {
    o[0] = bitsf(u.x << 16); o[1] = bitsf(u.x & 0xffff0000u);
    o[2] = bitsf(u.y << 16); o[3] = bitsf(u.y & 0xffff0000u);
    o[4] = bitsf(u.z << 16); o[5] = bitsf(u.z & 0xffff0000u);
    o[6] = bitsf(u.w << 16); o[7] = bitsf(u.w & 0xffff0000u);
}
// m204 bijective XCD-chunk swizzle: consecutive logical ids stay on one XCD
static __device__ __forceinline__ int xcd_swz(int bid, int nwg) {
    int q = nwg >> 3, r = nwg & 7;
    int x = bid & 7, idx = bid >> 3;
    return (x < r ? x * (q + 1) : r * (q + 1) + (x - r) * q) + idx;
}

// ============================ prep: zero + all bf16 casts (one launch) ============================
template<int SHIFT>
static __device__ __forceinline__ void cast_seg(const float* __restrict__ src,
                                                unsigned short* __restrict__ dst,
                                                int M, int K, long base, long total) {
    if (base >= total) return;
    int row = (int)(base >> SHIFT);
    int c   = (int)(base & ((1 << SHIFT) - 1));
    const float* srow = src + (size_t)row * K;
    unsigned short tmp[8];
    #pragma unroll
    for (int j = 0; j < 8; ++j) {
        int cc = c + j;
        float v = (row < M && cc < K) ? srow[cc] : 0.f;
        tmp[j] = f2bf(v);
    }
    *reinterpret_cast<int4*>(dst + base) = *reinterpret_cast<const int4*>(tmp);
}

__global__ __launch_bounds__(256) void prep(const float* __restrict__ x,
                                            const float* __restrict__ W1l,
                                            const float* __restrict__ W1r,
                                            const float* __restrict__ W2l,
                                            const float* __restrict__ W2r,
                                            unsigned short* __restrict__ xb,
                                            unsigned short* __restrict__ W1b,
                                            unsigned short* __restrict__ W2b,
                                            int* __restrict__ counts,
                                            int N, int Mpad,
                                            int ZB, int XB, int W1B, int W2B) {
    int bid = blockIdx.x;
    int tid = threadIdx.x;
    if (bid < ZB) {                              // counts = 1 (self-loop pre-count), ticket = 0
        int i = bid * 256 + tid;
        if (i < N) counts[i] = 1;
        else if (i == N) counts[N] = 0;          // counts[N] is the scan ticket
        return;
    }
    bid -= ZB;
    if (bid < XB) {                              // cast x -> xb [Mpad][512]
        long base = ((long)bid * 256 + tid) * 8;
        cast_seg<9>(x, xb, N, DIN, base, (long)Mpad * 512);
        return;
    }
    bid -= XB;
    if (bid < W1B) {
        long base = ((long)bid * 256 + tid) * 8;
        cast_seg<9>(W1l, W1b, H1, DIN, base, (long)H1 * 512);
        return;
    }
    bid -= W1B;
    if (bid < W1B) {
        long base = ((long)bid * 256 + tid) * 8;
        cast_seg<9>(W1r, W1b + (size_t)H1 * 512, H1, DIN, base, (long)H1 * 512);
        return;
    }
    bid -= W1B;
    if (bid < W2B) {
        long base = ((long)bid * 256 + tid) * 8;
        cast_seg<8>(W2l, W2b, H2, H1, base, (long)H2 * H1);
        return;
    }
    bid -= W2B;
    {
        long base = ((long)bid * 256 + tid) * 8;
        cast_seg<8>(W2r, W2b + (size_t)H2 * H1, H2, H1, base, (long)H2 * H1);
    }
}

// ============================ CSR build ============================

__global__ void count_deg(const int* __restrict__ dst, int E, int* __restrict__ counts) {
    int i = blockIdx.x * blockDim.x + threadIdx.x;
    if (i < E) atomicAdd(&counts[dst[i]], 1);
}

// two-level scan completed in ONE kernel via last-block ticket (coalesced 1024-wide scans)
__global__ __launch_bounds__(1024) void scan_all(const int* __restrict__ counts,
                                                 int* __restrict__ excl,
                                                 int* __restrict__ bsum,
                                                 int* __restrict__ done,
                                                 int* __restrict__ offsets,
                                                 int* __restrict__ cursor,
                                                 int n, int total_edges, int nb) {
    __shared__ int s[1024];
    __shared__ int sb[32];
    __shared__ int ticket;
    int tid = threadIdx.x;
    int bid = blockIdx.x;
    int i = bid * 1024 + tid;
    int v = (i < n) ? counts[i] : 0;
    s[tid] = v;
    __syncthreads();
    #pragma unroll
    for (int off = 1; off < 1024; off <<= 1) {
        int t = (tid >= off) ? s[tid - off] : 0;
        __syncthreads();
        s[tid] += t;
        __syncthreads();
    }
    if (i < n) excl[i] = s[tid] - v;
    if (tid == 1023) bsum[bid] = s[1023];
    __syncthreads();
    if (tid == 0) {
        __threadfence();
        ticket = __hip_atomic_fetch_add(done, 1, __ATOMIC_ACQ_REL, __HIP_MEMORY_SCOPE_AGENT);
    }
    __syncthreads();
    if (ticket == nb - 1) {                      // last block finishes the scan
        __threadfence();
        if (tid == 0) {
            int run = 0;
            for (int j = 0; j < nb; ++j) { int t = bsum[j]; sb[j] = run; run += t; }
        }
        __syncthreads();
        for (int j = tid; j < n; j += 1024) {    // coalesced
            int o = excl[j] + sb[j >> 10];
            offsets[j] = o;
            cursor[j]  = o;
        }
        if (tid == 0) offsets[n] = total_edges;
    }
}

// ============================ bf16 MFMA GEMM body (single-buffered; 32KB LDS -> high occupancy) ============================
template<int MODE>
static __device__ __forceinline__ void gemm_body(unsigned short* lA, unsigned short* lB,
                                                 const unsigned short* __restrict__ A,
                                                 const unsigned short* __restrict__ W,
                                                 const float* __restrict__ b_lo,
                                                 const float* __restrict__ b_hi,
                                                 int halfN,
                                                 unsigned short* __restrict__ Cb,
                                                 float* __restrict__ Cf,
                                                 int M, int Nc, int K,
                                                 int bm, int bn) {
    int tid  = threadIdx.x;
    int lane = tid & 63;
    int wid  = tid >> 6;
    int wr   = wid >> 1, wc = wid & 1;

    floatx4 acc[4][4] = {};

    int st_r = (lane >> 3);          // 0..7 within wave's 8-row group
    int st_p = (lane & 7);           // physical 16B slot within 128B row

    for (int k0 = 0; k0 < K; k0 += 64) {
        #pragma unroll
        for (int i = 0; i < 4; ++i) {
            int r = i * 32 + wid * 8 + st_r;           // tile row 0..127
            int s = st_p ^ (r & 7);                    // pre-swizzled source slot
            const unsigned short* ga = A + (size_t)(bm + r) * K + k0 + s * 8;
            const unsigned short* gb = W + (size_t)(bn + r) * K + k0 + s * 8;
            __builtin_amdgcn_global_load_lds(
                (const __attribute__((address_space(1))) void*)ga,
                (__attribute__((address_space(3))) void*)((char*)lA + i * 4096 + wid * 1024),
                16, 0, 0);
            __builtin_amdgcn_global_load_lds(
                (const __attribute__((address_space(1))) void*)gb,
                (__attribute__((address_space(3))) void*)((char*)lB + i * 4096 + wid * 1024),
                16, 0, 0);
        }
        __syncthreads();

        #pragma unroll
        for (int kk = 0; kk < 2; ++kk) {
            int sbase = kk * 4 + (lane >> 4);          // logical 16B slot 0..7
            short8 af[4], bf[4];
            #pragma unroll
            for (int ar = 0; ar < 4; ++ar) {
                int lr = wr * 64 + ar * 16 + (lane & 15);
                af[ar] = *reinterpret_cast<const short8*>(
                    (const char*)lA + lr * 128 + ((sbase ^ (lr & 7)) * 16));
            }
            #pragma unroll
            for (int bc = 0; bc < 4; ++bc) {
                int lc = wc * 64 + bc * 16 + (lane & 15);
                bf[bc] = *reinterpret_cast<const short8*>(
                    (const char*)lB + lc * 128 + ((sbase ^ (lc & 7)) * 16));
            }
            #pragma unroll
            for (int ar = 0; ar < 4; ++ar)
                #pragma unroll
                for (int bc = 0; bc < 4; ++bc)
                    acc[ar][bc] = __builtin_amdgcn_mfma_f32_16x16x32_bf16(
                        af[ar], bf[bc], acc[ar][bc], 0, 0, 0);
        }
        __syncthreads();
    }

    // epilogue: C/D layout col=lane&15, row=(lane>>4)*4+reg
    #pragma unroll
    for (int ar = 0; ar < 4; ++ar) {
        #pragma unroll
        for (int bc = 0; bc < 4; ++bc) {
            int col = bn + wc * 64 + bc * 16 + (lane & 15);
            float bv = (col < halfN) ? b_lo[col] : b_hi[col - halfN];
            #pragma unroll
            for (int r = 0; r < 4; ++r) {
                int row = bm + wr * 64 + ar * 16 + (lane >> 4) * 4 + r;
                if (row < M) {
                    float v = acc[ar][bc][r] + bv;
                    if (MODE == 1) {
                        Cb[(size_t)row * Nc + col] = f2bf(v);
                    } else {
                        if (col < halfN) Cb[(size_t)row * halfN + col] = f2bf(v);
                        else             Cf[(size_t)row * halfN + col - halfN] = v;
                    }
                }
            }
        }
    }
}

// layer-1 GEMM (XCD-swizzled) fused with edge scatter
__global__ __launch_bounds__(256) void gemm1_scatter(const unsigned short* __restrict__ A,
                                                     const unsigned short* __restrict__ W,
                                                     const float* __restrict__ b_lo,
                                                     const float* __restrict__ b_hi,
                                                     unsigned short* __restrict__ Cb,
                                                     const int* __restrict__ src,
                                                     const int* __restrict__ dst,
                                                     int E, int N,
                                                     int* __restrict__ cursor,
                                                     int* __restrict__ esrc,
                                                     int GB, int M, int Nc, int K) {
    __shared__ unsigned short lA[128 * 64];
    __shared__ unsigned short lB[128 * 64];
    int bid = blockIdx.x;
    if (bid < GB) {
        int lg = xcd_swz(bid, GB);          // same-bm tiles stay on one XCD's L2
        gemm_body<1>(lA, lB, A, W, b_lo, b_hi, Nc >> 1, Cb, nullptr, M, Nc, K,
                     (lg >> 2) * 128, (lg & 3) * 128);
    } else {
        int i = (bid - GB) * 256 + threadIdx.x;
        int total = E + N;
        if (i < total) {
            int d, s;
            if (i < E) { d = dst[i]; s = src[i]; }
            else       { d = i - E; s = i - E; }
            int pos = atomicAdd(&cursor[d], 1);
            esrc[pos] = s;
        }
    }
}

__global__ __launch_bounds__(256) void gemm2_k(const unsigned short* __restrict__ A,
                                               const unsigned short* __restrict__ W,
                                               const float* __restrict__ b_lo,
                                               const float* __restrict__ b_hi,
                                               int halfN,
                                               unsigned short* __restrict__ Cb,
                                               float* __restrict__ Cf,
                                               int nwg, int M, int Nc, int K) {
    __shared__ unsigned short lA[128 * 64];
    __shared__ unsigned short lB[128 * 64];
    int lg = xcd_swz(blockIdx.x, nwg);
    gemm_body<2>(lA, lB, A, W, b_lo, b_hi, halfN, Cb, Cf, M, Nc, K,
                 (lg >> 1) * 128, (lg & 1) * 128);
}

// ============================ Layer-1 edge phase ============================
// 4 nodes/block (1 wave each); 4 edge slots x 16 lanes; lane owns 16 ch.
// 2-edge unroll per slot per iter (2 row-loads in flight) + esrc prefetch.
__global__ __launch_bounds__(256) void gat_edge1(const unsigned short* __restrict__ xlr,
                                                 const float* __restrict__ att,
                                                 const float* __restrict__ bias,
                                                 const int* __restrict__ offsets,
                                                 const int* __restrict__ esrc,
                                                 unsigned short* __restrict__ hb,
                                                 int N) {
    int node = blockIdx.x * 4 + (threadIdx.x >> 6);
    int lane = threadIdx.x & 63;
    int sub  = lane >> 4;          // edge slot 0..3
    int ln   = lane & 15;
    int c0   = ln * 16;
    if (node >= N) {               // zero pad rows for the layer-2 GEMM
        if (sub == 0) {
            int4 z = {0, 0, 0, 0};
            int4* pp = reinterpret_cast<int4*>(&hb[(size_t)node * H1 + c0]);
            pp[0] = z; pp[1] = z;
        }
        return;
    }
    const unsigned short* xrrow = xlr + ((size_t)node << 9) + 256 + c0;
    float r_[16];
    cvt8(*reinterpret_cast<const uint4*>(xrrow),     r_);
    cvt8(*reinterpret_cast<const uint4*>(xrrow + 8), r_ + 8);
    float a_[16];
    #pragma unroll
    for (int j = 0; j < 4; ++j)
        *reinterpret_cast<float4*>(&a_[j * 4]) =
            *reinterpret_cast<const float4*>(&att[c0 + j * 4]);

    float d = 0.f;
    float ac[16];
    #pragma unroll
    for (int j = 0; j < 16; ++j) ac[j] = 0.f;

    int beg = offsets[node], end = offsets[node + 1];
    int k = beg + sub;
    // pipeline: rows for edges A(k), B(k+4) loaded; s for C(k+8), D(k+12) prefetched
    bool vA = (k      < end);
    bool vB = (k + 4  < end);
    bool vC = (k + 8  < end);
    bool vD = (k + 12 < end);
    int sA = esrc[vA ? k      : beg];
    int sB = esrc[vB ? k + 4  : beg];
    int sC = esrc[vC ? k + 8  : beg];
    int sD = esrc[vD ? k + 12 : beg];
    const unsigned short* rA = xlr + ((size_t)sA << 9) + c0;
    const unsigned short* rB = xlr + ((size_t)sB << 9) + c0;
    uint4 A0 = *reinterpret_cast<const uint4*>(rA);
    uint4 A1 = *reinterpret_cast<const uint4*>(rA + 8);
    uint4 B0 = *reinterpret_cast<const uint4*>(rB);
    uint4 B1 = *reinterpret_cast<const uint4*>(rB + 8);

    while (vA) {
        // issue next pair's row loads
        const unsigned short* rC = xlr + ((size_t)sC << 9) + c0;
        const unsigned short* rD = xlr + ((size_t)sD << 9) + c0;
        uint4 C0 = *reinterpret_cast<const uint4*>(rC);
        uint4 C1 = *reinterpret_cast<const uint4*>(rC + 8);
        uint4 D0 = *reinterpret_cast<const uint4*>(rD);
        uint4 D1 = *reinterpret_cast<const uint4*>(rD + 8);
        // prefetch s for the pair after that
        bool vE = (k + 16 < end);
        bool vF = (k + 20 < end);
        int sE = esrc[vE ? k + 16 : beg];
        int sF = esrc[vF ? k + 20 : beg];

        // compute edge A (valid by loop condition)
        float lA_[16];
        cvt8(A0, lA_); cvt8(A1, lA_ + 8);
        float pA0 = 0.f, pA1 = 0.f;
        // compute edge B (masked)
        float lB_[16];
        cvt8(B0, lB_); cvt8(B1, lB_ + 8);
        float pB0 = 0.f, pB1 = 0.f;
        #pragma unroll
        for (int j = 0; j < 8; ++j) {
            float eA0 = lA_[j]     + r_[j];     eA0 = fmaxf(eA0, NEG_SLOPE * eA0);
            float eA1 = lA_[j + 8] + r_[j + 8]; eA1 = fmaxf(eA1, NEG_SLOPE * eA1);
            pA0 = fmaf(eA0, a_[j], pA0);
            pA1 = fmaf(eA1, a_[j + 8], pA1);
            float eB0 = lB_[j]     + r_[j];     eB0 = fmaxf(eB0, NEG_SLOPE * eB0);
            float eB1 = lB_[j + 8] + r_[j + 8]; eB1 = fmaxf(eB1, NEG_SLOPE * eB1);
            pB0 = fmaf(eB0, a_[j], pB0);
            pB1 = fmaf(eB1, a_[j + 8], pB1);
        }
        float pA = pA0 + pA1;
        float pB = pB0 + pB1;
        pA += __shfl_xor(pA, 1, 2);          // head logit (2 lanes/head)
        pB += __shfl_xor(pB, 1, 2);
        float wA = __expf(pA);
        float wB = vB ? __expf(pB) : 0.f;    // mask invalid second edge
        d += wA + wB;
        #pragma unroll
        for (int j = 0; j < 16; ++j)
            ac[j] = fmaf(wA, lA_[j], fmaf(wB, lB_[j], ac[j]));

        A0 = C0; A1 = C1; B0 = D0; B1 = D1;
        sC = sE; sD = sF;
        vA = vC; vB = vD; vC = vE; vD = vF;
        k += 8;
    }

    #pragma unroll
    for (int off = 16; off <= 32; off <<= 1) {
        d += __shfl_xor(d, off, 64);
        #pragma unroll
        for (int j = 0; j < 16; ++j) ac[j] += __shfl_xor(ac[j], off, 64);
    }

    if (sub == 0) {
        float inv = 1.f / d;
        unsigned int ow[8];
        #pragma unroll
        for (int j = 0; j < 8; ++j) {
            float o0 = ac[2 * j]     * inv + bias[c0 + 2 * j];
            float o1 = ac[2 * j + 1] * inv + bias[c0 + 2 * j + 1];
            o0 = (o0 > 0.f) ? o0 : __expf(o0) - 1.f;   // ELU
            o1 = (o1 > 0.f) ? o1 : __expf(o1) - 1.f;
            ow[j] = (unsigned int)f2bf(o0) | ((unsigned int)f2bf(o1) << 16);
        }
        uint4* pp = reinterpret_cast<uint4*>(&hb[(size_t)node * H1 + c0]);
        pp[0] = make_uint4(ow[0], ow[1], ow[2], ow[3]);
        pp[1] = make_uint4(ow[4], ow[5], ow[6], ow[7]);
    }
}

// ============================ Layer-2 edge phase + log_softmax ============================
// 4 nodes/block; 4 edge slots x 16 lanes; lane owns 8 ch. 2-edge unroll per slot.
__global__ __launch_bounds__(256) void gat_edge2(const unsigned short* __restrict__ xl2b,
                                                 const float* __restrict__ xr2f,
                                                 const float* __restrict__ att,
                                                 const float* __restrict__ bias,
                                                 const int* __restrict__ offsets,
                                                 const int* __restrict__ esrc,
                                                 float* __restrict__ out,
                                                 int N) {
    int node = blockIdx.x * 4 + (threadIdx.x >> 6);
    if (node >= N) return;
    int lane = threadIdx.x & 63;
    int sub  = lane >> 4;
    int ln   = lane & 15;
    int c0   = ln * 8;

    float r_[8];
    *reinterpret_cast<float4*>(&r_[0]) =
        *reinterpret_cast<const float4*>(&xr2f[(size_t)node * H2 + c0]);
    *reinterpret_cast<float4*>(&r_[4]) =
        *reinterpret_cast<const float4*>(&xr2f[(size_t)node * H2 + c0 + 4]);
    float a_[8];
    *reinterpret_cast<float4*>(&a_[0]) = *reinterpret_cast<const float4*>(&att[c0]);
    *reinterpret_cast<float4*>(&a_[4]) = *reinterpret_cast<const float4*>(&att[c0 + 4]);

    float d = 0.f;
    float ac[8];
    #pragma unroll
    for (int j = 0; j < 8; ++j) ac[j] = 0.f;

    int beg = offsets[node], end = offsets[node + 1];
    int k = beg + sub;
    bool vA = (k      < end);
    bool vB = (k + 4  < end);
    bool vC = (k + 8  < end);
    bool vD = (k + 12 < end);
    int sA = esrc[vA ? k      : beg];
    int sB = esrc[vB ? k + 4  : beg];
    int sC = esrc[vC ? k + 8  : beg];
    int sD = esrc[vD ? k + 12 : beg];
    uint4 Av = *reinterpret_cast<const uint4*>(&xl2b[(size_t)sA * H2 + c0]);
    uint4 Bv = *reinterpret_cast<const uint4*>(&xl2b[(size_t)sB * H2 + c0]);

    while (vA) {
        uint4 Cv = *reinterpret_cast<const uint4*>(&xl2b[(size_t)sC * H2 + c0]);
        uint4 Dv = *reinterpret_cast<const uint4*>(&xl2b[(size_t)sD * H2 + c0]);
        bool vE = (k + 16 < end);
        bool vF = (k + 20 < end);
        int sE = esrc[vE ? k + 16 : beg];
        int sF = esrc[vF ? k + 20 : beg];

        float lA_[8], lB_[8];
        cvt8(Av, lA_);
        cvt8(Bv, lB_);
        float pA0 = 0.f, pA1 = 0.f, pB0 = 0.f, pB1 = 0.f;
        #pragma unroll
        for (int j = 0; j < 4; ++j) {
            float eA0 = lA_[j]     + r_[j];     eA0 = fmaxf(eA0, NEG_SLOPE * eA0);
            float eA1 = lA_[j + 4] + r_[j + 4]; eA1 = fmaxf(eA1, NEG_SLOPE * eA1);
            pA0 = fmaf(eA0, a_[j], pA0);
            pA1 = fmaf(eA1, a_[j + 4], pA1);
            float eB0 = lB_[j]     + r_[j];     eB0 = fmaxf(eB0, NEG_SLOPE * eB0);
            float eB1 = lB_[j + 4] + r_[j + 4]; eB1 = fmaxf(eB1, NEG_SLOPE * eB1);
            pB0 = fmaf(eB0, a_[j], pB0);
            pB1 = fmaf(eB1, a_[j + 4], pB1);
        }
        float pA = pA0 + pA1;
        float pB = pB0 + pB1;
        pA += __shfl_xor(pA, 1, 2);
        pB += __shfl_xor(pB, 1, 2);
        float wA = __expf(pA);
        float wB = vB ? __expf(pB) : 0.f;
        d += wA + wB;
        #pragma unroll
        for (int j = 0; j < 8; ++j)
            ac[j] = fmaf(wA, lA_[j], fmaf(wB, lB_[j], ac[j]));

        Av = Cv; Bv = Dv;
        sC = sE; sD = sF;
        vA = vC; vB = vD; vC = vE; vD = vF;
        k += 8;
    }

    #pragma unroll
    for (int off = 16; off <= 32; off <<= 1) {
        d += __shfl_xor(d, off, 64);
        #pragma unroll
        for (int j = 0; j < 8; ++j) ac[j] += __shfl_xor(ac[j], off, 64);
    }

    float inv = 1.f / d;
    float v[8];
    #pragma unroll
    for (int j = 0; j < 8; ++j) v[j] = ac[j] * inv + bias[c0 + j];
    float lm = v[0];
    #pragma unroll
    for (int j = 1; j < 8; ++j) lm = fmaxf(lm, v[j]);
    #pragma unroll
    for (int off = 1; off < 16; off <<= 1) lm = fmaxf(lm, __shfl_xor(lm, off, 16));
    float se = 0.f;
    #pragma unroll
    for (int j = 0; j < 8; ++j) se += __expf(v[j] - lm);
    #pragma unroll
    for (int off = 1; off < 16; off <<= 1) se += __shfl_xor(se, off, 16);
    float lz = lm + __logf(se);

    if (sub == 0) {
        float4 o0 = { v[0] - lz, v[1] - lz, v[2] - lz, v[3] - lz };
        float4 o1 = { v[4] - lz, v[5] - lz, v[6] - lz, v[7] - lz };
        float4* pp = reinterpret_cast<float4*>(&out[(size_t)node * H2 + c0]);
        pp[0] = o0; pp[1] = o1;
    }
}

// ============================ launch ============================

extern "C" void kernel_launch(void* const* d_in, const int* in_sizes, int n_in,
                              void* d_out, int out_size, void* d_ws, size_t ws_size,
                              hipStream_t stream) {
    const float* x     = (const float*)d_in[0];
    const int*   ei    = (const int*)d_in[1];
    const float* W1l   = (const float*)d_in[2];
    const float* b1l   = (const float*)d_in[3];
    const float* W1r   = (const float*)d_in[4];
    const float* b1r   = (const float*)d_in[5];
    const float* att1  = (const float*)d_in[6];
    const float* bias1 = (const float*)d_in[7];
    const float* W2l   = (const float*)d_in[8];
    const float* b2l   = (const float*)d_in[9];
    const float* W2r   = (const float*)d_in[10];
    const float* b2r   = (const float*)d_in[11];
    const float* att2  = (const float*)d_in[12];
    const float* bias2 = (const float*)d_in[13];
    float* out = (float*)d_out;

    const int N  = in_sizes[0] / DIN;       // 20000
    const int E  = in_sizes[1] / 2;         // 320000
    const int EN = E + N;
    const int Mpad = ((N + 127) / 128) * 128;   // 20096
    const int K1p  = 512;                   // DIN padded
    const int* srcIdx = ei;
    const int* dstIdx = ei + E;

    // workspace carve-up
    char* ws = (char*)d_ws;
    unsigned short* xb   = (unsigned short*)ws; ws += (size_t)Mpad * K1p * sizeof(short);
    unsigned short* W1b  = (unsigned short*)ws; ws += (size_t)(2 * H1) * K1p * sizeof(short);
    unsigned short* W2b  = (unsigned short*)ws; ws += (size_t)(2 * H2) * H1 * sizeof(short);
    unsigned short* xlr1 = (unsigned short*)ws; ws += (size_t)Mpad * (2 * H1) * sizeof(short);
    unsigned short* hb   = (unsigned short*)ws; ws += (size_t)Mpad * H1 * sizeof(short);
    unsigned short* xl2b = (unsigned short*)ws; ws += (size_t)Mpad * H2 * sizeof(short);
    float* xr2f = (float*)ws; ws += (size_t)Mpad * H2 * sizeof(float);
    int* counts  = (int*)ws;  ws += (size_t)(N + 1) * sizeof(int);   // counts[N] = scan ticket
    int* excl    = (int*)ws;  ws += (size_t)N * sizeof(int);
    int* bsum    = (int*)ws;  ws += 64 * sizeof(int);
    int* offsets = (int*)ws;  ws += (size_t)(N + 1) * sizeof(int);
    int* cursor  = (int*)ws;  ws += (size_t)N * sizeof(int);
    int* esrc    = (int*)ws;  ws += (size_t)EN * sizeof(int);

    const int ZB  = (N + 1 + 255) / 256;
    const int XB  = (int)(((long)Mpad * K1p / 8 + 255) / 256);
    const int W1B = (H1 * K1p / 8 + 255) / 256;
    const int W2B = (H2 * H1 / 8 + 255) / 256;
    const int nb  = (N + 1023) / 1024;

    // K1: zero + all casts
    prep<<<ZB + XB + 2 * W1B + 2 * W2B, 256, 0, stream>>>(
        x, W1l, W1r, W2l, W2r, xb, W1b, W2b, counts, N, Mpad, ZB, XB, W1B, W2B);

    // K2: degree count (self-loops pre-seeded)
    count_deg<<<(E + 255) / 256, 256, 0, stream>>>(dstIdx, E, counts);

    // K3: full scan -> offsets + cursor (ticketed, coalesced)
    scan_all<<<nb, 1024, 0, stream>>>(counts, excl, bsum, counts + N,
                                      offsets, cursor, N, EN, nb);

    // K4: layer-1 GEMM (xlr1 = x @ [W1l|W1r]^T + b, bf16 out)  ||  edge scatter
    const int GB = (Mpad / 128) * ((2 * H1) / 128);      // 628 gemm blocks
    const int SB = (EN + 255) / 256;
    gemm1_scatter<<<GB + SB, 256, 0, stream>>>(xb, W1b, b1l, b1r, xlr1,
                                               srcIdx, dstIdx, E, N, cursor, esrc,
                                               GB, Mpad, 2 * H1, K1p);

    // K5: layer-1 edge phase
    gat_edge1<<<Mpad / 4, 256, 0, stream>>>(xlr1, att1, bias1, offsets, esrc, hb, N);

    // K6: layer-2 GEMM: [xl2b(bf16) | xr2f(fp32)] = h @ [W2l|W2r]^T + b
    const int G2 = (Mpad / 128) * ((2 * H2) / 128);      // 314 blocks
    gemm2_k<<<G2, 256, 0, stream>>>(hb, W2b, b2l, b2r, H2, xl2b, xr2f, G2, N, 2 * H2, H1);

    // K7: layer-2 edge phase + log_softmax
    gat_edge2<<<(N + 3) / 4, 256, 0, stream>>>(xl2b, xr2f, att2, bias2, offsets, esrc, out, N);
}

// Round 12
// 150.287 us; speedup vs baseline: 1.0275x; 1.0275x over previous
//
#include <hip/hip_runtime.h>
#include <math.h>

#define DIN   500
#define H1    256   // heads(8) * dim_h(32)
#define H2    128   // heads(8) * dim_out(16)
#define NEG_SLOPE 0.2f

typedef __attribute__((ext_vector_type(8))) short short8;
typedef __attribute__((ext_vector_type(4))) float floatx4;

static __device__ __forceinline__ unsigned short f2bf(float f) {
    union { float f; unsigned int u; } x; x.f = f;
    unsigned int r = x.u + 0x7fffu + ((x.u >> 16) & 1u);   // RNE
    return (unsigned short)(r >> 16);
}
static __device__ __forceinline__ float bitsf(unsigned int i) {
    union { unsigned int i; float f; } x; x.i = i;
    return x.f;
}
// 4 dwords (8 bf16, channel-ordered lo/hi) -> 8 floats
static __device__ __forceinline__ void cvt8(uint4 u, float* o) {
    o[0] = bitsf(u.x << 16); o[1] = bitsf(u.x & 0xffff0000u);
    o[2] = bitsf(u.y << 16); o[3] = bitsf(u.y & 0xffff0000u);
    o[4] = bitsf(u.z << 16); o[5] = bitsf(u.z & 0xffff0000u);
    o[6] = bitsf(u.w << 16); o[7] = bitsf(u.w & 0xffff0000u);
}
// m204 bijective XCD-chunk swizzle: consecutive logical ids stay on one XCD
static __device__ __forceinline__ int xcd_swz(int bid, int nwg) {
    int q = nwg >> 3, r = nwg & 7;
    int x = bid & 7, idx = bid >> 3;
    return (x < r ? x * (q + 1) : r * (q + 1) + (x - r) * q) + idx;
}

// ============================ prep: zero + all bf16 casts (one launch) ============================
template<int SHIFT>
static __device__ __forceinline__ void cast_seg(const float* __restrict__ src,
                                                unsigned short* __restrict__ dst,
                                                int M, int K, long base, long total) {
    if (base >= total) return;
    int row = (int)(base >> SHIFT);
    int c   = (int)(base & ((1 << SHIFT) - 1));
    const float* srow = src + (size_t)row * K;
    unsigned short tmp[8];
    #pragma unroll
    for (int j = 0; j < 8; ++j) {
        int cc = c + j;
        float v = (row < M && cc < K) ? srow[cc] : 0.f;
        tmp[j] = f2bf(v);
    }
    *reinterpret_cast<int4*>(dst + base) = *reinterpret_cast<const int4*>(tmp);
}

__global__ __launch_bounds__(256) void prep(const float* __restrict__ x,
                                            const float* __restrict__ W1l,
                                            const float* __restrict__ W1r,
                                            const float* __restrict__ W2l,
                                            const float* __restrict__ W2r,
                                            unsigned short* __restrict__ xb,
                                            unsigned short* __restrict__ W1b,
                                            unsigned short* __restrict__ W2b,
                                            int* __restrict__ counts,
                                            int N, int Mpad,
                                            int ZB, int XB, int W1B, int W2B) {
    int bid = blockIdx.x;
    int tid = threadIdx.x;
    if (bid < ZB) {                              // counts = 1 (self-loop pre-count), ticket = 0
        int i = bid * 256 + tid;
        if (i < N) counts[i] = 1;
        else if (i == N) counts[N] = 0;          // counts[N] is the scan ticket
        return;
    }
    bid -= ZB;
    if (bid < XB) {                              // cast x -> xb [Mpad][512]
        long base = ((long)bid * 256 + tid) * 8;
        cast_seg<9>(x, xb, N, DIN, base, (long)Mpad * 512);
        return;
    }
    bid -= XB;
    if (bid < W1B) {
        long base = ((long)bid * 256 + tid) * 8;
        cast_seg<9>(W1l, W1b, H1, DIN, base, (long)H1 * 512);
        return;
    }
    bid -= W1B;
    if (bid < W1B) {
        long base = ((long)bid * 256 + tid) * 8;
        cast_seg<9>(W1r, W1b + (size_t)H1 * 512, H1, DIN, base, (long)H1 * 512);
        return;
    }
    bid -= W1B;
    if (bid < W2B) {
        long base = ((long)bid * 256 + tid) * 8;
        cast_seg<8>(W2l, W2b, H2, H1, base, (long)H2 * H1);
        return;
    }
    bid -= W2B;
    {
        long base = ((long)bid * 256 + tid) * 8;
        cast_seg<8>(W2r, W2b + (size_t)H2 * H1, H2, H1, base, (long)H2 * H1);
    }
}

// ============================ CSR build ============================

__global__ void count_deg(const int* __restrict__ dst, int E, int* __restrict__ counts) {
    int i = blockIdx.x * blockDim.x + threadIdx.x;
    if (i < E) atomicAdd(&counts[dst[i]], 1);
}

// two-level scan completed in ONE kernel via last-block ticket (coalesced 1024-wide scans)
__global__ __launch_bounds__(1024) void scan_all(const int* __restrict__ counts,
                                                 int* __restrict__ excl,
                                                 int* __restrict__ bsum,
                                                 int* __restrict__ done,
                                                 int* __restrict__ offsets,
                                                 int* __restrict__ cursor,
                                                 int n, int total_edges, int nb) {
    __shared__ int s[1024];
    __shared__ int sb[32];
    __shared__ int ticket;
    int tid = threadIdx.x;
    int bid = blockIdx.x;
    int i = bid * 1024 + tid;
    int v = (i < n) ? counts[i] : 0;
    s[tid] = v;
    __syncthreads();
    #pragma unroll
    for (int off = 1; off < 1024; off <<= 1) {
        int t = (tid >= off) ? s[tid - off] : 0;
        __syncthreads();
        s[tid] += t;
        __syncthreads();
    }
    if (i < n) excl[i] = s[tid] - v;
    if (tid == 1023) bsum[bid] = s[1023];
    __syncthreads();
    if (tid == 0) {
        __threadfence();
        ticket = __hip_atomic_fetch_add(done, 1, __ATOMIC_ACQ_REL, __HIP_MEMORY_SCOPE_AGENT);
    }
    __syncthreads();
    if (ticket == nb - 1) {                      // last block finishes the scan
        __threadfence();
        if (tid == 0) {
            int run = 0;
            for (int j = 0; j < nb; ++j) { int t = bsum[j]; sb[j] = run; run += t; }
        }
        __syncthreads();
        for (int j = tid; j < n; j += 1024) {    // coalesced
            int o = excl[j] + sb[j >> 10];
            offsets[j] = o;
            cursor[j]  = o;
        }
        if (tid == 0) offsets[n] = total_edges;
    }
}

// ============================ bf16 MFMA GEMM body (single-buffered; 32KB LDS -> high occupancy) ============================
template<int MODE>
static __device__ __forceinline__ void gemm_body(unsigned short* lA, unsigned short* lB,
                                                 const unsigned short* __restrict__ A,
                                                 const unsigned short* __restrict__ W,
                                                 const float* __restrict__ b_lo,
                                                 const float* __restrict__ b_hi,
                                                 int halfN,
                                                 unsigned short* __restrict__ Cb,
                                                 float* __restrict__ Cf,
                                                 int M, int Nc, int K,
                                                 int bm, int bn) {
    int tid  = threadIdx.x;
    int lane = tid & 63;
    int wid  = tid >> 6;
    int wr   = wid >> 1, wc = wid & 1;

    floatx4 acc[4][4] = {};

    int st_r = (lane >> 3);          // 0..7 within wave's 8-row group
    int st_p = (lane & 7);           // physical 16B slot within 128B row

    for (int k0 = 0; k0 < K; k0 += 64) {
        #pragma unroll
        for (int i = 0; i < 4; ++i) {
            int r = i * 32 + wid * 8 + st_r;           // tile row 0..127
            int s = st_p ^ (r & 7);                    // pre-swizzled source slot
            const unsigned short* ga = A + (size_t)(bm + r) * K + k0 + s * 8;
            const unsigned short* gb = W + (size_t)(bn + r) * K + k0 + s * 8;
            __builtin_amdgcn_global_load_lds(
                (const __attribute__((address_space(1))) void*)ga,
                (__attribute__((address_space(3))) void*)((char*)lA + i * 4096 + wid * 1024),
                16, 0, 0);
            __builtin_amdgcn_global_load_lds(
                (const __attribute__((address_space(1))) void*)gb,
                (__attribute__((address_space(3))) void*)((char*)lB + i * 4096 + wid * 1024),
                16, 0, 0);
        }
        __syncthreads();

        #pragma unroll
        for (int kk = 0; kk < 2; ++kk) {
            int sbase = kk * 4 + (lane >> 4);          // logical 16B slot 0..7
            short8 af[4], bf[4];
            #pragma unroll
            for (int ar = 0; ar < 4; ++ar) {
                int lr = wr * 64 + ar * 16 + (lane & 15);
                af[ar] = *reinterpret_cast<const short8*>(
                    (const char*)lA + lr * 128 + ((sbase ^ (lr & 7)) * 16));
            }
            #pragma unroll
            for (int bc = 0; bc < 4; ++bc) {
                int lc = wc * 64 + bc * 16 + (lane & 15);
                bf[bc] = *reinterpret_cast<const short8*>(
                    (const char*)lB + lc * 128 + ((sbase ^ (lc & 7)) * 16));
            }
            #pragma unroll
            for (int ar = 0; ar < 4; ++ar)
                #pragma unroll
                for (int bc = 0; bc < 4; ++bc)
                    acc[ar][bc] = __builtin_amdgcn_mfma_f32_16x16x32_bf16(
                        af[ar], bf[bc], acc[ar][bc], 0, 0, 0);
        }
        __syncthreads();
    }

    // epilogue: C/D layout col=lane&15, row=(lane>>4)*4+reg
    #pragma unroll
    for (int ar = 0; ar < 4; ++ar) {
        #pragma unroll
        for (int bc = 0; bc < 4; ++bc) {
            int col = bn + wc * 64 + bc * 16 + (lane & 15);
            float bv = (col < halfN) ? b_lo[col] : b_hi[col - halfN];
            #pragma unroll
            for (int r = 0; r < 4; ++r) {
                int row = bm + wr * 64 + ar * 16 + (lane >> 4) * 4 + r;
                if (row < M) {
                    float v = acc[ar][bc][r] + bv;
                    if (MODE == 1) {
                        Cb[(size_t)row * Nc + col] = f2bf(v);
                    } else {
                        if (col < halfN) Cb[(size_t)row * halfN + col] = f2bf(v);
                        else             Cf[(size_t)row * halfN + col - halfN] = v;
                    }
                }
            }
        }
    }
}

// layer-1 GEMM (XCD-swizzled) fused with edge scatter
__global__ __launch_bounds__(256) void gemm1_scatter(const unsigned short* __restrict__ A,
                                                     const unsigned short* __restrict__ W,
                                                     const float* __restrict__ b_lo,
                                                     const float* __restrict__ b_hi,
                                                     unsigned short* __restrict__ Cb,
                                                     const int* __restrict__ src,
                                                     const int* __restrict__ dst,
                                                     int E, int N,
                                                     int* __restrict__ cursor,
                                                     int* __restrict__ esrc,
                                                     int GB, int M, int Nc, int K) {
    __shared__ unsigned short lA[128 * 64];
    __shared__ unsigned short lB[128 * 64];
    int bid = blockIdx.x;
    if (bid < GB) {
        int lg = xcd_swz(bid, GB);          // same-bm tiles stay on one XCD's L2
        gemm_body<1>(lA, lB, A, W, b_lo, b_hi, Nc >> 1, Cb, nullptr, M, Nc, K,
                     (lg >> 2) * 128, (lg & 3) * 128);
    } else {
        int i = (bid - GB) * 256 + threadIdx.x;
        int total = E + N;
        if (i < total) {
            int d, s;
            if (i < E) { d = dst[i]; s = src[i]; }
            else       { d = i - E; s = i - E; }
            int pos = atomicAdd(&cursor[d], 1);
            esrc[pos] = s;
        }
    }
}

__global__ __launch_bounds__(256) void gemm2_k(const unsigned short* __restrict__ A,
                                               const unsigned short* __restrict__ W,
                                               const float* __restrict__ b_lo,
                                               const float* __restrict__ b_hi,
                                               int halfN,
                                               unsigned short* __restrict__ Cb,
                                               float* __restrict__ Cf,
                                               int nwg, int M, int Nc, int K) {
    __shared__ unsigned short lA[128 * 64];
    __shared__ unsigned short lB[128 * 64];
    int lg = xcd_swz(blockIdx.x, nwg);
    gemm_body<2>(lA, lB, A, W, b_lo, b_hi, halfN, Cb, Cf, M, Nc, K,
                 (lg >> 1) * 128, (lg & 1) * 128);
}

// ============================ Layer-1 edge phase ============================
// 4 nodes/block (1 wave each); 4 edge slots x 16 lanes; lane owns 16 ch (head = ln>>1).
// Direct exp (logits O(sigma~1.5), fp32 exp safe) + 2-stage prefetch.
__global__ __launch_bounds__(256) void gat_edge1(const unsigned short* __restrict__ xlr,
                                                 const float* __restrict__ att,
                                                 const float* __restrict__ bias,
                                                 const int* __restrict__ offsets,
                                                 const int* __restrict__ esrc,
                                                 unsigned short* __restrict__ hb,
                                                 int N) {
    int node = blockIdx.x * 4 + (threadIdx.x >> 6);
    int lane = threadIdx.x & 63;
    int sub  = lane >> 4;          // edge slot 0..3
    int ln   = lane & 15;
    int c0   = ln * 16;
    if (node >= N) {               // zero pad rows for the layer-2 GEMM
        if (sub == 0) {
            int4 z = {0, 0, 0, 0};
            int4* pp = reinterpret_cast<int4*>(&hb[(size_t)node * H1 + c0]);
            pp[0] = z; pp[1] = z;
        }
        return;
    }
    const unsigned short* xrrow = xlr + ((size_t)node << 9) + 256 + c0;
    float r_[16];
    cvt8(*reinterpret_cast<const uint4*>(xrrow),     r_);
    cvt8(*reinterpret_cast<const uint4*>(xrrow + 8), r_ + 8);
    float a_[16];
    #pragma unroll
    for (int j = 0; j < 4; ++j)
        *reinterpret_cast<float4*>(&a_[j * 4]) =
            *reinterpret_cast<const float4*>(&att[c0 + j * 4]);

    float d = 0.f;
    float ac[16];
    #pragma unroll
    for (int j = 0; j < 16; ++j) ac[j] = 0.f;

    int beg = offsets[node], end = offsets[node + 1];
    int k = beg + sub;
    bool v_c = (k < end);
    bool v_n = (k + 4 < end);
    int s_c = esrc[v_c ? k : beg];
    int s_n = esrc[v_n ? k + 4 : beg];
    const unsigned short* rc = xlr + ((size_t)s_c << 9) + c0;
    uint4 c0v = *reinterpret_cast<const uint4*>(rc);
    uint4 c1v = *reinterpret_cast<const uint4*>(rc + 8);

    while (v_c) {
        const unsigned short* rn = xlr + ((size_t)s_n << 9) + c0;
        uint4 n0v = *reinterpret_cast<const uint4*>(rn);
        uint4 n1v = *reinterpret_cast<const uint4*>(rn + 8);
        bool v_nn = (k + 8 < end);
        int s_nn = esrc[v_nn ? k + 8 : beg];

        float l_[16];
        cvt8(c0v, l_); cvt8(c1v, l_ + 8);
        float p0 = 0.f, p1 = 0.f;
        #pragma unroll
        for (int j = 0; j < 8; ++j) {
            float e0 = l_[j]     + r_[j];     e0 = fmaxf(e0, NEG_SLOPE * e0);
            float e1 = l_[j + 8] + r_[j + 8]; e1 = fmaxf(e1, NEG_SLOPE * e1);
            p0 = fmaf(e0, a_[j], p0);
            p1 = fmaf(e1, a_[j + 8], p1);
        }
        float p = p0 + p1;
        p += __shfl_xor(p, 1, 2);           // head logit (2 lanes/head)
        float w = __expf(p);
        d += w;
        #pragma unroll
        for (int j = 0; j < 16; ++j) ac[j] = fmaf(w, l_[j], ac[j]);

        c0v = n0v; c1v = n1v;
        s_c = s_n; s_n = s_nn;
        v_c = v_n; v_n = v_nn;
        k += 4;
    }

    #pragma unroll
    for (int off = 16; off <= 32; off <<= 1) {
        d += __shfl_xor(d, off, 64);
        #pragma unroll
        for (int j = 0; j < 16; ++j) ac[j] += __shfl_xor(ac[j], off, 64);
    }

    if (sub == 0) {
        float inv = 1.f / d;
        unsigned int ow[8];
        #pragma unroll
        for (int j = 0; j < 8; ++j) {
            float o0 = ac[2 * j]     * inv + bias[c0 + 2 * j];
            float o1 = ac[2 * j + 1] * inv + bias[c0 + 2 * j + 1];
            o0 = (o0 > 0.f) ? o0 : __expf(o0) - 1.f;   // ELU
            o1 = (o1 > 0.f) ? o1 : __expf(o1) - 1.f;
            ow[j] = (unsigned int)f2bf(o0) | ((unsigned int)f2bf(o1) << 16);
        }
        uint4* pp = reinterpret_cast<uint4*>(&hb[(size_t)node * H1 + c0]);
        pp[0] = make_uint4(ow[0], ow[1], ow[2], ow[3]);
        pp[1] = make_uint4(ow[4], ow[5], ow[6], ow[7]);
    }
}

// ============================ Layer-2 edge phase + log_softmax ============================
__global__ __launch_bounds__(256) void gat_edge2(const unsigned short* __restrict__ xl2b,
                                                 const float* __restrict__ xr2f,
                                                 const float* __restrict__ att,
                                                 const float* __restrict__ bias,
                                                 const int* __restrict__ offsets,
                                                 const int* __restrict__ esrc,
                                                 float* __restrict__ out,
                                                 int N) {
    int node = blockIdx.x * 4 + (threadIdx.x >> 6);
    if (node >= N) return;
    int lane = threadIdx.x & 63;
    int sub  = lane >> 4;
    int ln   = lane & 15;
    int c0   = ln * 8;

    float r_[8];
    *reinterpret_cast<float4*>(&r_[0]) =
        *reinterpret_cast<const float4*>(&xr2f[(size_t)node * H2 + c0]);
    *reinterpret_cast<float4*>(&r_[4]) =
        *reinterpret_cast<const float4*>(&xr2f[(size_t)node * H2 + c0 + 4]);
    float a_[8];
    *reinterpret_cast<float4*>(&a_[0]) = *reinterpret_cast<const float4*>(&att[c0]);
    *reinterpret_cast<float4*>(&a_[4]) = *reinterpret_cast<const float4*>(&att[c0 + 4]);

    float d = 0.f;
    float ac[8];
    #pragma unroll
    for (int j = 0; j < 8; ++j) ac[j] = 0.f;

    int beg = offsets[node], end = offsets[node + 1];
    int k = beg + sub;
    bool v_c = (k < end);
    bool v_n = (k + 4 < end);
    int s_c = esrc[v_c ? k : beg];
    int s_n = esrc[v_n ? k + 4 : beg];
    uint4 cv = *reinterpret_cast<const uint4*>(&xl2b[(size_t)s_c * H2 + c0]);

    while (v_c) {
        uint4 nv = *reinterpret_cast<const uint4*>(&xl2b[(size_t)s_n * H2 + c0]);
        bool v_nn = (k + 8 < end);
        int s_nn = esrc[v_nn ? k + 8 : beg];

        float l_[8];
        cvt8(cv, l_);
        float p0 = 0.f, p1 = 0.f;
        #pragma unroll
        for (int j = 0; j < 4; ++j) {
            float e0 = l_[j]     + r_[j];     e0 = fmaxf(e0, NEG_SLOPE * e0);
            float e1 = l_[j + 4] + r_[j + 4]; e1 = fmaxf(e1, NEG_SLOPE * e1);
            p0 = fmaf(e0, a_[j], p0);
            p1 = fmaf(e1, a_[j + 4], p1);
        }
        float p = p0 + p1;
        p += __shfl_xor(p, 1, 2);
        float w = __expf(p);
        d += w;
        #pragma unroll
        for (int j = 0; j < 8; ++j) ac[j] = fmaf(w, l_[j], ac[j]);

        cv = nv;
        s_c = s_n; s_n = s_nn;
        v_c = v_n; v_n = v_nn;
        k += 4;
    }

    #pragma unroll
    for (int off = 16; off <= 32; off <<= 1) {
        d += __shfl_xor(d, off, 64);
        #pragma unroll
        for (int j = 0; j < 8; ++j) ac[j] += __shfl_xor(ac[j], off, 64);
    }

    float inv = 1.f / d;
    float v[8];
    #pragma unroll
    for (int j = 0; j < 8; ++j) v[j] = ac[j] * inv + bias[c0 + j];
    float lm = v[0];
    #pragma unroll
    for (int j = 1; j < 8; ++j) lm = fmaxf(lm, v[j]);
    #pragma unroll
    for (int off = 1; off < 16; off <<= 1) lm = fmaxf(lm, __shfl_xor(lm, off, 16));
    float se = 0.f;
    #pragma unroll
    for (int j = 0; j < 8; ++j) se += __expf(v[j] - lm);
    #pragma unroll
    for (int off = 1; off < 16; off <<= 1) se += __shfl_xor(se, off, 16);
    float lz = lm + __logf(se);

    if (sub == 0) {
        float4 o0 = { v[0] - lz, v[1] - lz, v[2] - lz, v[3] - lz };
        float4 o1 = { v[4] - lz, v[5] - lz, v[6] - lz, v[7] - lz };
        float4* pp = reinterpret_cast<float4*>(&out[(size_t)node * H2 + c0]);
        pp[0] = o0; pp[1] = o1;
    }
}

// ============================ launch ============================

extern "C" void kernel_launch(void* const* d_in, const int* in_sizes, int n_in,
                              void* d_out, int out_size, void* d_ws, size_t ws_size,
                              hipStream_t stream) {
    const float* x     = (const float*)d_in[0];
    const int*   ei    = (const int*)d_in[1];
    const float* W1l   = (const float*)d_in[2];
    const float* b1l   = (const float*)d_in[3];
    const float* W1r   = (const float*)d_in[4];
    const float* b1r   = (const float*)d_in[5];
    const float* att1  = (const float*)d_in[6];
    const float* bias1 = (const float*)d_in[7];
    const float* W2l   = (const float*)d_in[8];
    const float* b2l   = (const float*)d_in[9];
    const float* W2r   = (const float*)d_in[10];
    const float* b2r   = (const float*)d_in[11];
    const float* att2  = (const float*)d_in[12];
    const float* bias2 = (const float*)d_in[13];
    float* out = (float*)d_out;

    const int N  = in_sizes[0] / DIN;       // 20000
    const int E  = in_sizes[1] / 2;         // 320000
    const int EN = E + N;
    const int Mpad = ((N + 127) / 128) * 128;   // 20096
    const int K1p  = 512;                   // DIN padded
    const int* srcIdx = ei;
    const int* dstIdx = ei + E;

    // workspace carve-up
    char* ws = (char*)d_ws;
    unsigned short* xb   = (unsigned short*)ws; ws += (size_t)Mpad * K1p * sizeof(short);
    unsigned short* W1b  = (unsigned short*)ws; ws += (size_t)(2 * H1) * K1p * sizeof(short);
    unsigned short* W2b  = (unsigned short*)ws; ws += (size_t)(2 * H2) * H1 * sizeof(short);
    unsigned short* xlr1 = (unsigned short*)ws; ws += (size_t)Mpad * (2 * H1) * sizeof(short);
    unsigned short* hb   = (unsigned short*)ws; ws += (size_t)Mpad * H1 * sizeof(short);
    unsigned short* xl2b = (unsigned short*)ws; ws += (size_t)Mpad * H2 * sizeof(short);
    float* xr2f = (float*)ws; ws += (size_t)Mpad * H2 * sizeof(float);
    int* counts  = (int*)ws;  ws += (size_t)(N + 1) * sizeof(int);   // counts[N] = scan ticket
    int* excl    = (int*)ws;  ws += (size_t)N * sizeof(int);
    int* bsum    = (int*)ws;  ws += 64 * sizeof(int);
    int* offsets = (int*)ws;  ws += (size_t)(N + 1) * sizeof(int);
    int* cursor  = (int*)ws;  ws += (size_t)N * sizeof(int);
    int* esrc    = (int*)ws;  ws += (size_t)EN * sizeof(int);

    const int ZB  = (N + 1 + 255) / 256;
    const int XB  = (int)(((long)Mpad * K1p / 8 + 255) / 256);
    const int W1B = (H1 * K1p / 8 + 255) / 256;
    const int W2B = (H2 * H1 / 8 + 255) / 256;
    const int nb  = (N + 1023) / 1024;

    // K1: zero + all casts
    prep<<<ZB + XB + 2 * W1B + 2 * W2B, 256, 0, stream>>>(
        x, W1l, W1r, W2l, W2r, xb, W1b, W2b, counts, N, Mpad, ZB, XB, W1B, W2B);

    // K2: degree count (self-loops pre-seeded)
    count_deg<<<(E + 255) / 256, 256, 0, stream>>>(dstIdx, E, counts);

    // K3: full scan -> offsets + cursor (ticketed, coalesced)
    scan_all<<<nb, 1024, 0, stream>>>(counts, excl, bsum, counts + N,
                                      offsets, cursor, N, EN, nb);

    // K4: layer-1 GEMM (xlr1 = x @ [W1l|W1r]^T + b, bf16 out)  ||  edge scatter
    const int GB = (Mpad / 128) * ((2 * H1) / 128);      // 628 gemm blocks
    const int SB = (EN + 255) / 256;
    gemm1_scatter<<<GB + SB, 256, 0, stream>>>(xb, W1b, b1l, b1r, xlr1,
                                               srcIdx, dstIdx, E, N, cursor, esrc,
                                               GB, Mpad, 2 * H1, K1p);

    // K5: layer-1 edge phase
    gat_edge1<<<Mpad / 4, 256, 0, stream>>>(xlr1, att1, bias1, offsets, esrc, hb, N);

    // K6: layer-2 GEMM: [xl2b(bf16) | xr2f(fp32)] = h @ [W2l|W2r]^T + b
    const int G2 = (Mpad / 128) * ((2 * H2) / 128);      // 314 blocks
    gemm2_k<<<G2, 256, 0, stream>>>(hb, W2b, b2l, b2r, H2, xl2b, xr2f, G2, N, 2 * H2, H1);

    // K7: layer-2 edge phase + log_softmax
    gat_edge2<<<(N + 3) / 4, 256, 0, stream>>>(xl2b, xr2f, att2, bias2, offsets, esrc, out, N);
}